// Round 9
// baseline (315.676 us; speedup 1.0000x reference)
//
#include <hip/hip_runtime.h>
#include <hip/hip_bf16.h>

typedef __attribute__((ext_vector_type(8))) short short8;
typedef __attribute__((ext_vector_type(4))) float floatx4;
typedef unsigned int u32;

#define NN 4096

static __device__ __forceinline__ unsigned f2bf_rne(float x) {
    union { float f; unsigned u; } v; v.f = x;
    unsigned r = v.u + 0x7fffu + ((v.u >> 16) & 1u);
    return r >> 16;
}
static __device__ __forceinline__ float bf2f(unsigned hi) {
    union { unsigned u; float f; } v; v.u = hi << 16; return v.f;
}

// ---- prep (fused wc, round-0 structure; mm-loop unrolled for ILP): per-block
// computes Wc=W1@W2, w1*alpha; then G = X@Wc (bf16 hi/lo MFMA) -> Gt bf16
// [b*64+c][4096] row-major; lv/rv fp32.
__global__ __launch_bounds__(256, 4)
void prep_kernel(const float* __restrict__ X,
                 const float* __restrict__ W1,
                 const float* __restrict__ W2,
                 const float* __restrict__ alpha,
                 unsigned short* __restrict__ Gt,
                 float* __restrict__ lv,
                 float* __restrict__ rv) {
    __shared__ __align__(16) char sm[53248];
    float* W1s  = (float*)sm;                 // [64][68]
    float* W2s  = (float*)(sm + 17408);       // [64][68]
    float* Wcst = (float*)(sm + 34816);       // Wc^T: [n][k] stride 68
    float* w1s  = (float*)(sm + 52224);       // [128]
    float* als  = (float*)(sm + 52736);       // [128]
    float* GsT  = (float*)sm;                 // epilogue reuse: [64][68]

    const int t = threadIdx.x;
    const int row0 = blockIdx.x * 64;         // flat b*N + n
    const int b = row0 >> 12, n0 = row0 & (NN - 1);
    const int w = t >> 6, lane = t & 63;
    const int m = lane & 15, q = lane >> 4;

    // issue X loads early (consumed much later)
    const int row = row0 + w * 16 + m;
    const float* xp = X + (size_t)row * 64;
    float4 x0 = *(const float4*)(xp + q * 8);
    float4 x1 = *(const float4*)(xp + q * 8 + 4);
    float4 x2 = *(const float4*)(xp + 32 + q * 8);
    float4 x3 = *(const float4*)(xp + 32 + q * 8 + 4);

    #pragma unroll
    for (int s = 0; s < 4; ++s) {
        int idx = s * 1024 + t * 4;
        int r = idx >> 6, cc = idx & 63;
        *(float4*)&W1s[r * 68 + cc] = *(const float4*)(W1 + idx);
        *(float4*)&W2s[r * 68 + cc] = *(const float4*)(W2 + idx);
    }
    if (t < 128) als[t] = alpha[t];
    __syncthreads();

    // Wc^T: thread (k = t>>2, nq = t&3) computes Wc[k][n], n in [nq*16, nq*16+16)
    {
        const int k = t >> 2, nq = t & 3;
        float acc[16];
        #pragma unroll
        for (int i = 0; i < 16; ++i) acc[i] = 0.f;
        #pragma unroll 4
        for (int mm = 0; mm < 64; ++mm) {
            float w1v = W1s[k * 68 + mm];
            #pragma unroll
            for (int i = 0; i < 16; ++i)
                acc[i] += w1v * W2s[mm * 68 + nq * 16 + i];
        }
        #pragma unroll
        for (int i = 0; i < 16; ++i)
            Wcst[(nq * 16 + i) * 68 + k] = acc[i];
    }
    if (t < 64) {   // w1a = {W1@aL, W1@aR}
        float sl = 0.f, sr = 0.f;
        #pragma unroll 4
        for (int cc2 = 0; cc2 < 64; ++cc2) {
            float wv = W1s[t * 68 + cc2];
            sl += wv * als[cc2];
            sr += wv * als[64 + cc2];
        }
        w1s[t] = sl; w1s[64 + t] = sr;
    }
    __syncthreads();

    const float xs[16] = {x0.x,x0.y,x0.z,x0.w, x1.x,x1.y,x1.z,x1.w,
                          x2.x,x2.y,x2.z,x2.w, x3.x,x3.y,x3.z,x3.w};

    // lv/rv fp32
    float pl = 0.f, pr = 0.f;
    #pragma unroll
    for (int ks = 0; ks < 2; ++ks)
        #pragma unroll
        for (int j = 0; j < 8; ++j) {
            int k = ks * 32 + q * 8 + j;
            float xv = xs[ks * 8 + j];
            pl += xv * w1s[k];
            pr += xv * w1s[64 + k];
        }
    pl += __shfl_xor(pl, 16, 64); pl += __shfl_xor(pl, 32, 64);
    pr += __shfl_xor(pr, 16, 64); pr += __shfl_xor(pr, 32, 64);
    if (q == 0) { lv[row] = pl; rv[row] = pr; }

    // bf16 hi/lo A-fragments
    short8 ah[2], al[2];
    #pragma unroll
    for (int ks = 0; ks < 2; ++ks)
        #pragma unroll
        for (int j = 0; j < 8; ++j) {
            float f = xs[ks * 8 + j];
            unsigned hb = f2bf_rne(f);
            float res = f - bf2f(hb);
            ah[ks][j] = (short)hb;
            al[ks][j] = (short)f2bf_rne(res);
        }

    // B-frags from Wcst
    short8 bfr[4][2];
    #pragma unroll
    for (int nt = 0; nt < 4; ++nt)
        #pragma unroll
        for (int ks = 0; ks < 2; ++ks) {
            const float* wp = &Wcst[(nt * 16 + m) * 68 + ks * 32 + q * 8];
            float4 w0 = *(const float4*)wp;
            float4 w1 = *(const float4*)(wp + 4);
            short8 bf;
            bf[0] = (short)f2bf_rne(w0.x); bf[1] = (short)f2bf_rne(w0.y);
            bf[2] = (short)f2bf_rne(w0.z); bf[3] = (short)f2bf_rne(w0.w);
            bf[4] = (short)f2bf_rne(w1.x); bf[5] = (short)f2bf_rne(w1.y);
            bf[6] = (short)f2bf_rne(w1.z); bf[7] = (short)f2bf_rne(w1.w);
            bfr[nt][ks] = bf;
        }

    floatx4 acc[4] = {{0,0,0,0},{0,0,0,0},{0,0,0,0},{0,0,0,0}};
    #pragma unroll
    for (int ks = 0; ks < 2; ++ks)
        #pragma unroll
        for (int nt = 0; nt < 4; ++nt) {
            acc[nt] = __builtin_amdgcn_mfma_f32_16x16x32_bf16(ah[ks], bfr[nt][ks], acc[nt], 0, 0, 0);
            acc[nt] = __builtin_amdgcn_mfma_f32_16x16x32_bf16(al[ks], bfr[nt][ks], acc[nt], 0, 0, 0);
        }

    __syncthreads();    // all Wcst/W1s reads done; sm@0 reused as GsT
    #pragma unroll
    for (int nt = 0; nt < 4; ++nt)
        #pragma unroll
        for (int rg = 0; rg < 4; ++rg)
            GsT[(nt * 16 + m) * 68 + w * 16 + q * 4 + rg] = acc[nt][rg];
    __syncthreads();
    unsigned* Gu = (unsigned*)Gt;
    #pragma unroll
    for (int it2 = 0; it2 < 8; ++it2) {
        int c2 = (t >> 5) + it2 * 8;
        int np = t & 31;
        unsigned lo = f2bf_rne(GsT[c2 * 68 + 2 * np]);
        unsigned hi = f2bf_rne(GsT[c2 * 68 + 2 * np + 1]);
        Gu[(((((size_t)(b * 64 + c2)) << 12) + n0) >> 1) + np] = lo | (hi << 16);
    }
}

// ---- attn_main v9 = v8 loop body, but grid 512 = (it 64 x jh 2 x b 4,
// b fastest) so TWO 16-wave blocks co-reside per CU (LDS 61440 x2 = 120K,
// VGPR<=64 via launch_bounds(1024,8)) -> 8 waves/SIMD in 2 INDEPENDENT
// barrier domains: when one block stalls at its barrier/vmem, the other
// issues. Each group covers 512 j (16 chunks). Partials -> reduce kernel.
// Kept from v8 (verified): in-reg consumer-layout E, VALU dsum, 3-buffer
// ring, lgkm-only barrier (vmem prefetch stays in flight). New: setprio(1)
// around MFMA cluster.
__global__ __launch_bounds__(1024, 8)
void attn_main(const float* __restrict__ A,
               const unsigned short* __restrict__ Gt,
               const float* __restrict__ lv,
               const float* __restrict__ rv,
               float* __restrict__ pout) {
    __shared__ __align__(16) char sm[61440];   // Gs[3 buf][4 grp][64*40] u16; epilogue red reuse
    unsigned short* Gs = (unsigned short*)sm;

    const int bx = blockIdx.x;
    const int b  = bx & 3;
    const int jh = (bx >> 2) & 1;
    const int it = bx >> 3;
    const int i0 = it * 64;
    const int t = threadIdx.x;
    const int wave = t >> 6, lane = t & 63;
    const int grp = wave >> 2, wsub = wave & 3;
    const int m = lane & 15, q = lane >> 4;
    const int irE = wsub * 16 + m;             // consumer/E row
    const int irS = wsub * 16 + (lane >> 2);   // staging row
    const int jseg = lane & 3;

    const int gidx  = jh * 4 + grp;            // global 512-j window id
    const int jbase = gidx * 512;

    const float* aRow = A + (size_t)(i0 + irE) * NN + jbase + q * 8;
    const float* rvp  = rv + (size_t)b * NN + jbase + q * 8;
    const unsigned short* gRow = Gt + (((size_t)(b * 64 + irS)) << 12) + jbase + jseg * 8;

    const float li = lv[b * NN + i0 + irE] * 1.44269504f;   // fold log2e
    const float li001 = li * 0.01f;
    const bool diag_grp = ((i0 >> 9) == gidx);
    const int jd = (i0 + irE) - jbase;

    const int soff = irS * 40 + jseg * 8;      // staging offset within group tile
    unsigned short* GsG = Gs + grp * 2560;     // + buf*10240 selects ring buffer

    // prologue: G(0)->buf0; G(1)->sg; A/rv chunks 0 (E set) and 1 (O set)
    short8 sg = *(const short8*)(gRow);
    float4 a0E = *(const float4*)(aRow);
    float4 a1E = *(const float4*)(aRow + 4);
    float4 r0E = *(const float4*)(rvp);
    float4 r1E = *(const float4*)(rvp + 4);
    float4 a0O = *(const float4*)(aRow + 32);
    float4 a1O = *(const float4*)(aRow + 36);
    float4 r0O = *(const float4*)(rvp + 32);
    float4 r1O = *(const float4*)(rvp + 36);
    *(short8*)&GsG[soff] = sg;                 // buf0 = G(0)
    sg = *(const short8*)(gRow + 32);          // G(1)
    asm volatile("s_waitcnt lgkmcnt(0)" ::: "memory");
    __builtin_amdgcn_s_barrier();
    __builtin_amdgcn_sched_barrier(0);

    floatx4 acc0 = {0,0,0,0}, acc1 = {0,0,0,0}, acc2 = {0,0,0,0}, acc3 = {0,0,0,0};
    float dsum = 0.f;

    auto genE = [&](float4 a0, float4 a1, float4 r0, float4 r1, int chunk) -> short8 {
        float aa[8] = {a0.x, a0.y, a0.z, a0.w, a1.x, a1.y, a1.z, a1.w};
        if (diag_grp && ((jd >> 5) == chunk)) {            // adj diag := 1
            const int dd = jd - (chunk * 32 + q * 8);
            #pragma unroll
            for (int e = 0; e < 8; ++e) if (dd == e) aa[e] = 1.0f;
        }
        const float rr[8] = {r0.x, r0.y, r0.z, r0.w, r1.x, r1.y, r1.z, r1.w};
        unsigned up[8];
        #pragma unroll
        for (int e = 0; e < 8; ++e) {
            float s = fmaxf(li * rr[e], li001 * rr[e]);    // leaky(li*r)
            float ev = __builtin_amdgcn_exp2f(s) * aa[e];
            unsigned u = __float_as_uint(ev) + 0x8000u;
            up[e] = u;
            dsum += __uint_as_float(u & 0xffff0000u);      // den = same bf16 vals
        }
        union { unsigned u[4]; short8 s8; } cv;
        cv.u[0] = __builtin_amdgcn_perm(up[1], up[0], 0x07060302u);
        cv.u[1] = __builtin_amdgcn_perm(up[3], up[2], 0x07060302u);
        cv.u[2] = __builtin_amdgcn_perm(up[5], up[4], 0x07060302u);
        cv.u[3] = __builtin_amdgcn_perm(up[7], up[6], 0x07060302u);
        return cv.s8;
    };

    for (int cc = 0; cc < 16; cc += 2) {
        // ---- even chunk cc: read buf[cc%3], publish G(cc+1)->buf[(cc+1)%3] ----
        {
            *(short8*)&GsG[((cc + 1) % 3) * 10240 + soff] = sg;       // publish G(cc+1)
            { const int jn = (cc + 2 < 16) ? (cc + 2) * 32 : 0;       // fetch G(cc+2)
              sg = *(const short8*)(gRow + jn); }
            const short8 afr = genE(a0E, a1E, r0E, r1E, cc);
            { const int jn = (cc + 2 < 16) ? (cc + 2) * 32 : 0;       // reload E set <- cc+2
              a0E = *(const float4*)(aRow + jn);
              a1E = *(const float4*)(aRow + jn + 4);
              r0E = *(const float4*)(rvp + jn);
              r1E = *(const float4*)(rvp + jn + 4); }
            const unsigned short* rb = &GsG[(cc % 3) * 10240];
            const short8 b0 = *(const short8*)&rb[( m) * 40 + q * 8];
            const short8 b1 = *(const short8*)&rb[(16 + m) * 40 + q * 8];
            const short8 b2 = *(const short8*)&rb[(32 + m) * 40 + q * 8];
            const short8 b3 = *(const short8*)&rb[(48 + m) * 40 + q * 8];
            __builtin_amdgcn_s_setprio(1);
            acc0 = __builtin_amdgcn_mfma_f32_16x16x32_bf16(afr, b0, acc0, 0, 0, 0);
            acc1 = __builtin_amdgcn_mfma_f32_16x16x32_bf16(afr, b1, acc1, 0, 0, 0);
            acc2 = __builtin_amdgcn_mfma_f32_16x16x32_bf16(afr, b2, acc2, 0, 0, 0);
            acc3 = __builtin_amdgcn_mfma_f32_16x16x32_bf16(afr, b3, acc3, 0, 0, 0);
            __builtin_amdgcn_s_setprio(0);
            asm volatile("s_waitcnt lgkmcnt(0)" ::: "memory");        // ds ops only
            __builtin_amdgcn_s_barrier();                             // vmem stays in flight
            __builtin_amdgcn_sched_barrier(0);
        }
        // ---- odd chunk cc+1: read buf[(cc+1)%3], publish G(cc+2)->buf[(cc+2)%3] ----
        {
            *(short8*)&GsG[((cc + 2) % 3) * 10240 + soff] = sg;       // publish G(cc+2)
            { const int jn = (cc + 3 < 16) ? (cc + 3) * 32 : 0;       // fetch G(cc+3)
              sg = *(const short8*)(gRow + jn); }
            const short8 afr = genE(a0O, a1O, r0O, r1O, cc + 1);
            { const int jn = (cc + 3 < 16) ? (cc + 3) * 32 : 0;       // reload O set <- cc+3
              a0O = *(const float4*)(aRow + jn);
              a1O = *(const float4*)(aRow + jn + 4);
              r0O = *(const float4*)(rvp + jn);
              r1O = *(const float4*)(rvp + jn + 4); }
            const unsigned short* rb = &GsG[((cc + 1) % 3) * 10240];
            const short8 b0 = *(const short8*)&rb[( m) * 40 + q * 8];
            const short8 b1 = *(const short8*)&rb[(16 + m) * 40 + q * 8];
            const short8 b2 = *(const short8*)&rb[(32 + m) * 40 + q * 8];
            const short8 b3 = *(const short8*)&rb[(48 + m) * 40 + q * 8];
            __builtin_amdgcn_s_setprio(1);
            acc0 = __builtin_amdgcn_mfma_f32_16x16x32_bf16(afr, b0, acc0, 0, 0, 0);
            acc1 = __builtin_amdgcn_mfma_f32_16x16x32_bf16(afr, b1, acc1, 0, 0, 0);
            acc2 = __builtin_amdgcn_mfma_f32_16x16x32_bf16(afr, b2, acc2, 0, 0, 0);
            acc3 = __builtin_amdgcn_mfma_f32_16x16x32_bf16(afr, b3, acc3, 0, 0, 0);
            __builtin_amdgcn_s_setprio(0);
            asm volatile("s_waitcnt lgkmcnt(0)" ::: "memory");
            __builtin_amdgcn_s_barrier();
            __builtin_amdgcn_sched_barrier(0);
        }
    }

    // den: reduce over the 4 q-lanes of each row
    dsum += __shfl_xor(dsum, 16, 64);
    dsum += __shfl_xor(dsum, 32, 64);

    // ---- epilogue: two-pass cross-group reduction in LDS -> f32 partials ----
    __syncthreads();                           // full drain once; sm reused as red
    float* red = (float*)sm;                   // [2][64][68]; col 64 holds den
    const int il = t >> 4, c4 = t & 15;
    float4 osum = {0.f, 0.f, 0.f, 0.f};
    float dtot = 0.f;
    #pragma unroll
    for (int pass = 0; pass < 2; ++pass) {
        if ((grp >> 1) == pass) {
            float* rp_ = red + (grp & 1) * 4352;
            #pragma unroll
            for (int nt = 0; nt < 4; ++nt) {
                floatx4 av = nt == 0 ? acc0 : nt == 1 ? acc1 : nt == 2 ? acc2 : acc3;
                #pragma unroll
                for (int rg = 0; rg < 4; ++rg)
                    rp_[(wsub * 16 + q * 4 + rg) * 68 + nt * 16 + m] = av[rg];
            }
            if (q == 0) rp_[(wsub * 16 + m) * 68 + 64] = dsum;
        }
        __syncthreads();
        {
            float4 v0 = *(const float4*)&red[il * 68 + c4 * 4];
            float4 v1 = *(const float4*)&red[4352 + il * 68 + c4 * 4];
            osum.x += v0.x + v1.x; osum.y += v0.y + v1.y;
            osum.z += v0.z + v1.z; osum.w += v0.w + v1.w;
            dtot += red[il * 68 + 64] + red[4352 + il * 68 + 64];
        }
        __syncthreads();
    }
    float* pb = pout + (size_t)bx * 4352;      // [64][68], col 64 = den
    *(float4*)&pb[il * 68 + c4 * 4] = osum;
    if (c4 == 0) pb[il * 68 + 64] = dtot;
}

// ---- attn_reduce: grid 256 = (it 64, b 4), 256 thr. Sums the 2 j-half
// partials, divides by summed den, writes out.
__global__ __launch_bounds__(256, 4)
void attn_reduce(const float* __restrict__ pout,
                 float* __restrict__ out) {
    const int bx = blockIdx.x;
    const int it = bx & 63, b = bx >> 6;
    const int t = threadIdx.x;
    const int row = t >> 2, quad = t & 3;

    const float* base0 = pout + (size_t)((it << 3) | (0 << 2) | b) * 4352 + row * 68;
    const float* base1 = pout + (size_t)((it << 3) | (1 << 2) | b) * 4352 + row * 68;

    float den = base0[64] + base1[64];
    const float rinv = 1.0f / den;

    float* op = out + (((size_t)(b * NN + it * 64 + row)) << 6) + quad * 16;
    #pragma unroll
    for (int f = 0; f < 4; ++f) {
        const float4 v0 = *(const float4*)&base0[quad * 16 + f * 4];
        const float4 v1 = *(const float4*)&base1[quad * 16 + f * 4];
        float4 o;
        o.x = (v0.x + v1.x) * rinv;
        o.y = (v0.y + v1.y) * rinv;
        o.z = (v0.z + v1.z) * rinv;
        o.w = (v0.w + v1.w) * rinv;
        *(float4*)(op + f * 4) = o;
    }
}

extern "C" void kernel_launch(void* const* d_in, const int* in_sizes, int n_in,
                              void* d_out, int out_size, void* d_ws, size_t ws_size,
                              hipStream_t stream) {
    const float* X     = (const float*)d_in[0];
    const float* A     = (const float*)d_in[1];
    const float* W1    = (const float*)d_in[2];
    const float* W2    = (const float*)d_in[3];
    const float* alpha = (const float*)d_in[4];
    float* out = (float*)d_out;

    char* ws = (char*)d_ws;
    unsigned short* Gt = (unsigned short*)(ws);            // 2 MiB (row-major)
    float* lvp  = (float*)(ws + 2097152);                  // 64 KiB
    float* rvp  = (float*)(ws + 2097152 + 65536);          // 64 KiB
    float* pout = (float*)(ws + 2097152 + 131072);         // 512*4352*4 = 8.9 MiB

    prep_kernel<<<256, 256, 0, stream>>>(X, W1, W2, alpha, Gt, lvp, rvp);
    attn_main<<<512, 1024, 0, stream>>>(A, Gt, lvp, rvp, pout);
    attn_reduce<<<256, 256, 0, stream>>>(pout, out);
}